// Round 1
// baseline (1210.091 us; speedup 1.0000x reference)
//
#include <hip/hip_runtime.h>
#include <stdint.h>

typedef __attribute__((ext_vector_type(8))) short short8;   // 8 x bf16 (4 VGPRs)
typedef __attribute__((ext_vector_type(4))) float f32x4;    // MFMA accumulator

__device__ __forceinline__ unsigned short f2bf(float f) {
  union { float f; unsigned int u; } v;
  v.f = f;
  // round-to-nearest-even fp32 -> bf16
  return (unsigned short)((v.u + 0x7fffu + ((v.u >> 16) & 1u)) >> 16);
}

// async global->LDS, 16B per lane; LDS dest = wave-uniform base + lane*16
__device__ __forceinline__ void load16(const unsigned short* g, unsigned short* l) {
  __builtin_amdgcn_global_load_lds(
      (const __attribute__((address_space(1))) unsigned int*)g,
      (__attribute__((address_space(3))) unsigned int*)l, 16, 0, 0);
}

// ---------------- pass 1: all fp32 -> bf16 converts in ONE kernel -----------
__global__ void convert_all_kernel(const float* __restrict__ x, unsigned short* __restrict__ xb,
                                   const float* __restrict__ W, unsigned short* __restrict__ wb,
                                   const float* __restrict__ lb, unsigned short* __restrict__ lbb) {
  const int stride = gridDim.x * blockDim.x;
  const int i0 = blockIdx.x * blockDim.x + threadIdx.x;
  for (int i = i0; i < 16777216; i += stride) {           // x: 67108864 / 4
    float4 v = reinterpret_cast<const float4*>(x)[i];
    ushort4 o;
    o.x = f2bf(v.x); o.y = f2bf(v.y); o.z = f2bf(v.z); o.w = f2bf(v.w);
    reinterpret_cast<ushort4*>(xb)[i] = o;
  }
  for (int i = i0; i < 4194304; i += stride) {            // W: 16777216 / 4
    float4 v = reinterpret_cast<const float4*>(W)[i];
    ushort4 o;
    o.x = f2bf(v.x); o.y = f2bf(v.y); o.z = f2bf(v.z); o.w = f2bf(v.w);
    reinterpret_cast<ushort4*>(wb)[i] = o;
  }
  for (int i = i0; i < 131072; i += stride) {             // lora_b: 524288 / 4
    float4 v = reinterpret_cast<const float4*>(lb)[i];
    ushort4 o;
    o.x = f2bf(v.x); o.y = f2bf(v.y); o.z = f2bf(v.z); o.w = f2bf(v.w);
    reinterpret_cast<ushort4*>(lbb)[i] = o;
  }
}

// ---------------- pass 2: t = SCALING * x @ lora_a^T (per adapter) ----------
// one wave per 16-row strip; MFMA 16x16x32, N=16, K=4096
__global__ void lora_t_kernel(const unsigned short* __restrict__ xb,
                              const float* __restrict__ lora_a,
                              unsigned short* __restrict__ tb) {
  const int t = threadIdx.x;
  const int lane = t & 63;
  const int w = t >> 6;
  const int quad = lane >> 4;
  const int m16 = lane & 15;
  const int r0 = (blockIdx.x * 4 + w) << 4;   // first row of this wave's strip
  const int a = r0 >> 11;                     // adapter = row / 2048
  const unsigned short* xrow = xb + (size_t)(r0 + m16) * 4096 + (quad << 3);
  const float* arow = lora_a + (size_t)(a * 16 + m16) * 4096 + (quad << 3);
  f32x4 acc = {0.f, 0.f, 0.f, 0.f};
#pragma unroll 2
  for (int k = 0; k < 4096; k += 32) {
    short8 af = *(const short8*)(xrow + k);          // A[m=lane&15][k=quad*8+j]
    float4 f0 = *(const float4*)(arow + k);          // B[n=lane&15][k=quad*8+j]
    float4 f1 = *(const float4*)(arow + k + 4);
    short8 bf;
    bf[0] = (short)f2bf(f0.x); bf[1] = (short)f2bf(f0.y);
    bf[2] = (short)f2bf(f0.z); bf[3] = (short)f2bf(f0.w);
    bf[4] = (short)f2bf(f1.x); bf[5] = (short)f2bf(f1.y);
    bf[6] = (short)f2bf(f1.z); bf[7] = (short)f2bf(f1.w);
    acc = __builtin_amdgcn_mfma_f32_16x16x32_bf16(af, bf, acc, 0, 0, 0);
  }
  // C/D layout: col(lane&15)=r index, row=quad*4+reg = x-row offset
#pragma unroll
  for (int r = 0; r < 4; r++)
    tb[(size_t)(r0 + quad * 4 + r) * 16 + m16] = f2bf(acc[r] * 2.0f);
}

// ---------------- pass 3: out = x @ W^T + t @ lora_b^T ----------------------
// 256x256 tile, BK=32, 8 waves (2x4), per-wave 128x64 output (acc[8][4]).
// 4-slot LDS K-tile ring, counted vmcnt(8) (never drained in steady state),
// ONE raw s_barrier per K-step, setprio around the MFMA cluster.
//
// Race ledger (per iteration t, slot s=t&3):
//  RAW: each wave's own vmcnt(8) before the barrier guarantees ITS tile-t
//       loads landed; barrier => all waves' tile-t loads landed before any
//       ds_read of slot s.
//  WAR: stage(t+3) writes slot (t-1)&3. Every wave's ds_reads of that slot
//       (iteration t-1) complete before its MFMAs (compiler lgkm waits),
//       which precede the iteration-t barrier in program order; stage(t+3)
//       issues only after that barrier.
//  Tail: t=126 -> vmcnt(4), t=127 -> vmcnt(0); staging stops at tile 127.
__global__ __launch_bounds__(512, 2)
void lora_gemm_kernel(const unsigned short* __restrict__ xb,
                      const unsigned short* __restrict__ wb,
                      const unsigned short* __restrict__ tb,
                      const unsigned short* __restrict__ lbb,
                      float* __restrict__ out) {
  __shared__ unsigned short As[4][8192];   // 4 slots x 256 rows x 32 cols bf16
  __shared__ unsigned short Bs[4][8192];   // 128 KiB total
  const int tid = threadIdx.x;
  const int lane = tid & 63;
  const int w = tid >> 6;
  const int quad = lane >> 4;
  const int m16 = lane & 15;
  const int wr = w >> 2, wc = w & 3;

  // XCD-bijective swizzle (1024 blocks, 1024 % 8 == 0); colTile inner so an
  // XCD's concurrent blocks share A panels in its private L2.
  const int bswz = ((blockIdx.x & 7) << 7) | (blockIdx.x >> 3);
  const int rowTile = bswz >> 4;           // 0..63
  const int colTile = bswz & 15;           // 0..15
  const int rowBase = rowTile << 8;
  const int colBase = colTile << 8;
  const int wRow = rowBase + wr * 128;
  const int wCol = colBase + wc * 64;

  f32x4 acc[8][4];

  // ---- accumulator init = LoRA delta: t[256x16] @ lb[256x16]^T (K=16 pad) --
  // Done BEFORE staging so the compiler's vmcnt(0) for these loads does not
  // drain the K-tile prefetch queue.
  {
    const int aIdx = rowBase >> 11;        // whole 256-row tile is one adapter
    short8 z = {0, 0, 0, 0, 0, 0, 0, 0};
    f32x4 cz = {0.f, 0.f, 0.f, 0.f};
    short8 atf[8], btf[4];
#pragma unroll
    for (int mi = 0; mi < 8; mi++) {
      if (quad < 2)   // k = quad*8+j < 16 valid, upper half zero-padded
        atf[mi] = *(const short8*)(tb + (size_t)(wRow + mi * 16 + m16) * 16 + quad * 8);
      else
        atf[mi] = z;
    }
#pragma unroll
    for (int ni = 0; ni < 4; ni++) {
      if (quad < 2)
        btf[ni] = *(const short8*)(lbb + ((size_t)aIdx * 4096 + (wCol + ni * 16 + m16)) * 16 + quad * 8);
      else
        btf[ni] = z;
    }
#pragma unroll
    for (int mi = 0; mi < 8; mi++)
#pragma unroll
      for (int ni = 0; ni < 4; ni++)
        acc[mi][ni] = __builtin_amdgcn_mfma_f32_16x16x32_bf16(atf[mi], btf[ni], cz, 0, 0, 0);
  }

  // ---- staging: thread tid owns chunks tid and tid+512 of each 16 KB slot.
  // chunk c -> row c>>2 (0..255), 16B col-chunk c&3. LDS dest is linear, so a
  // wave's 64 chunks = wave-uniform base + lane*16  (global_load_lds rule).
  const unsigned short* gA = xb + (size_t)(rowBase + (tid >> 2)) * 4096 + (tid & 3) * 8;
  const unsigned short* gB = wb + (size_t)(colBase + (tid >> 2)) * 4096 + (tid & 3) * 8;

#define STAGE(T) do { const int s_ = (T) & 3;                                   \
    load16(gA + (size_t)(T) * 32,                      &As[s_][0] + tid * 8);   \
    load16(gA + (size_t)(T) * 32 + (size_t)128 * 4096, &As[s_][0] + (tid + 512) * 8); \
    load16(gB + (size_t)(T) * 32,                      &Bs[s_][0] + tid * 8);   \
    load16(gB + (size_t)(T) * 32 + (size_t)128 * 4096, &Bs[s_][0] + (tid + 512) * 8); } while (0)

  STAGE(0); STAGE(1); STAGE(2);            // 3-deep prefetch (12 vmem ops)

  const int aoff = (wr * 128 + m16) * 32 + quad * 8;  // row stride 32 ush = 64 B
  const int boff = (wc * 64 + m16) * 32 + quad * 8;   // -> uniform bank spread

  for (int t = 0; t < 128; ++t) {
    if (t < 126)       asm volatile("s_waitcnt vmcnt(8)" ::: "memory");
    else if (t == 126) asm volatile("s_waitcnt vmcnt(4)" ::: "memory");
    else               asm volatile("s_waitcnt vmcnt(0)" ::: "memory");
    __builtin_amdgcn_s_barrier();
    asm volatile("" ::: "memory");
    if (t + 3 < 128) STAGE(t + 3);         // into slot freed at this barrier

    const unsigned short* Ap = &As[t & 3][0] + aoff;
    const unsigned short* Bp = &Bs[t & 3][0] + boff;
    short8 a[8], b[4];
#pragma unroll
    for (int ni = 0; ni < 4; ni++) b[ni] = *(const short8*)(Bp + ni * 512);
#pragma unroll
    for (int mi = 0; mi < 8; mi++) a[mi] = *(const short8*)(Ap + mi * 512);
    __builtin_amdgcn_s_setprio(1);
#pragma unroll
    for (int mi = 0; mi < 8; mi++)
#pragma unroll
      for (int ni = 0; ni < 4; ni++)
        acc[mi][ni] = __builtin_amdgcn_mfma_f32_16x16x32_bf16(a[mi], b[ni], acc[mi][ni], 0, 0, 0);
    __builtin_amdgcn_s_setprio(0);
    asm volatile("" ::: "memory");         // ds_reads may not sink past here
  }
#undef STAGE

  // ---- epilogue: C/D layout col=lane&15, row=quad*4+reg; fp32 store --------
#pragma unroll
  for (int mi = 0; mi < 8; mi++) {
    const int row0 = wRow + mi * 16 + quad * 4;
#pragma unroll
    for (int ni = 0; ni < 4; ni++) {
      const int col = wCol + ni * 16 + m16;
      float* p = out + (size_t)row0 * 4096 + col;
#pragma unroll
      for (int r = 0; r < 4; r++)
        p[(size_t)r * 4096] = acc[mi][ni][r];
    }
  }
}

extern "C" void kernel_launch(void* const* d_in, const int* in_sizes, int n_in,
                              void* d_out, int out_size, void* d_ws, size_t ws_size,
                              hipStream_t stream) {
  const float* x  = (const float*)d_in[0];   // [8,2048,4096]
  const float* W  = (const float*)d_in[1];   // [4096,4096] (out,in)
  const float* la = (const float*)d_in[2];   // [8,16,4096]
  const float* lb = (const float*)d_in[3];   // [8,4096,16]
  float* out = (float*)d_out;                // [8,2048,4096] fp32

  const size_t NX  = 8ull * 2048 * 4096;     // 67108864
  const size_t NW  = 4096ull * 4096;         // 16777216
  const size_t NT  = 16384ull * 16;          // 262144
  const size_t NLB = 8ull * 4096 * 16;       // 524288
  unsigned short* xb  = (unsigned short*)d_ws;
  unsigned short* wbf = xb + NX;
  unsigned short* tb  = wbf + NW;
  unsigned short* lbb = tb + NT;
  if (ws_size < (NX + NW + NT + NLB) * sizeof(unsigned short)) return;

  convert_all_kernel<<<2048, 256, 0, stream>>>(x, xb, W, wbf, lb, lbb);
  lora_t_kernel<<<256, 256, 0, stream>>>(xb, la, tb);
  lora_gemm_kernel<<<1024, 512, 0, stream>>>(xb, wbf, tb, lbb, out);
}

// Round 2
// 1092.450 us; speedup vs baseline: 1.1077x; 1.1077x over previous
//
#include <hip/hip_runtime.h>
#include <stdint.h>

typedef __attribute__((ext_vector_type(8))) short short8;   // 8 x bf16 (4 VGPRs)
typedef __attribute__((ext_vector_type(4))) float f32x4;    // MFMA accumulator

__device__ __forceinline__ unsigned short f2bf(float f) {
  union { float f; unsigned int u; } v;
  v.f = f;
  // round-to-nearest-even fp32 -> bf16
  return (unsigned short)((v.u + 0x7fffu + ((v.u >> 16) & 1u)) >> 16);
}

// async global->LDS, 16B per lane; LDS dest = wave-uniform base + lane*16
__device__ __forceinline__ void load16(const unsigned short* g, unsigned short* l) {
  __builtin_amdgcn_global_load_lds(
      (const __attribute__((address_space(1))) unsigned int*)g,
      (__attribute__((address_space(3))) unsigned int*)l, 16, 0, 0);
}

// ---------------- pass 1: all fp32 -> bf16 converts in ONE kernel -----------
__global__ void convert_all_kernel(const float* __restrict__ x, unsigned short* __restrict__ xb,
                                   const float* __restrict__ W, unsigned short* __restrict__ wb,
                                   const float* __restrict__ lb, unsigned short* __restrict__ lbb) {
  const int stride = gridDim.x * blockDim.x;
  const int i0 = blockIdx.x * blockDim.x + threadIdx.x;
  for (int i = i0; i < 16777216; i += stride) {           // x: 67108864 / 4
    float4 v = reinterpret_cast<const float4*>(x)[i];
    ushort4 o;
    o.x = f2bf(v.x); o.y = f2bf(v.y); o.z = f2bf(v.z); o.w = f2bf(v.w);
    reinterpret_cast<ushort4*>(xb)[i] = o;
  }
  for (int i = i0; i < 4194304; i += stride) {            // W: 16777216 / 4
    float4 v = reinterpret_cast<const float4*>(W)[i];
    ushort4 o;
    o.x = f2bf(v.x); o.y = f2bf(v.y); o.z = f2bf(v.z); o.w = f2bf(v.w);
    reinterpret_cast<ushort4*>(wb)[i] = o;
  }
  for (int i = i0; i < 131072; i += stride) {             // lora_b: 524288 / 4
    float4 v = reinterpret_cast<const float4*>(lb)[i];
    ushort4 o;
    o.x = f2bf(v.x); o.y = f2bf(v.y); o.z = f2bf(v.z); o.w = f2bf(v.w);
    reinterpret_cast<ushort4*>(lbb)[i] = o;
  }
}

// ---------------- pass 2: t = SCALING * x @ lora_a^T (per adapter) ----------
__global__ void lora_t_kernel(const unsigned short* __restrict__ xb,
                              const float* __restrict__ lora_a,
                              unsigned short* __restrict__ tb) {
  const int t = threadIdx.x;
  const int lane = t & 63;
  const int w = t >> 6;
  const int quad = lane >> 4;
  const int m16 = lane & 15;
  const int r0 = (blockIdx.x * 4 + w) << 4;   // first row of this wave's strip
  const int a = r0 >> 11;                     // adapter = row / 2048
  const unsigned short* xrow = xb + (size_t)(r0 + m16) * 4096 + (quad << 3);
  const float* arow = lora_a + (size_t)(a * 16 + m16) * 4096 + (quad << 3);
  f32x4 acc = {0.f, 0.f, 0.f, 0.f};
#pragma unroll 2
  for (int k = 0; k < 4096; k += 32) {
    short8 af = *(const short8*)(xrow + k);
    float4 f0 = *(const float4*)(arow + k);
    float4 f1 = *(const float4*)(arow + k + 4);
    short8 bf;
    bf[0] = (short)f2bf(f0.x); bf[1] = (short)f2bf(f0.y);
    bf[2] = (short)f2bf(f0.z); bf[3] = (short)f2bf(f0.w);
    bf[4] = (short)f2bf(f1.x); bf[5] = (short)f2bf(f1.y);
    bf[6] = (short)f2bf(f1.z); bf[7] = (short)f2bf(f1.w);
    acc = __builtin_amdgcn_mfma_f32_16x16x32_bf16(af, bf, acc, 0, 0, 0);
  }
#pragma unroll
  for (int r = 0; r < 4; r++)
    tb[(size_t)(r0 + quad * 4 + r) * 16 + m16] = f2bf(acc[r] * 2.0f);
}

// ---------------- pass 3: out = x @ W^T + t @ lora_b^T ----------------------
// 8-phase 256x256 template (m201 structure): BK=64, 8 waves (2M x 4N),
// per-wave 128x64 output (acc[8][4]), 2 LDS K-tile buffers (128 KiB),
// 4 phases per K-tile, disjoint acc-quadrant per phase, XOR-swizzled LDS.
//
// LDS layout (per [256][64] bf16 tile): chunk (row, j) holds global 16B-chunk
// (row, j ^ (row&7)).  Staging keeps LDS dest LINEAR (global_load_lds rule)
// and pre-swizzles the GLOBAL source column; reads apply the same XOR.
//
// Race ledger (tile t, buffers p=t&1):
//  RAW: phase-4 vmcnt(0) (loads issued in phase 1, ~3 phases old -> no fresh
//       drain) + closing barrier => tile t+1 fully landed before any read.
//  WAR: stage(t+1) targets buf[(t+1)&1] = buf[(t-1)&1]; every wave's reads of
//       that buffer completed at its phase-4(t-1) lgkmcnt(0), which precedes
//       that phase's closing barrier; stage issues after that barrier.
__global__ __launch_bounds__(512, 2)
void lora_gemm_kernel(const unsigned short* __restrict__ xb,
                      const unsigned short* __restrict__ wb,
                      const unsigned short* __restrict__ tb,
                      const unsigned short* __restrict__ lbb,
                      float* __restrict__ out) {
  __shared__ unsigned short As[2][16384];   // [2 dbuf][256 rows x 64 cols]
  __shared__ unsigned short Bs[2][16384];   // 128 KiB total
  const int tid = threadIdx.x;
  const int lane = tid & 63;
  const int w = tid >> 6;
  const int quad = lane >> 4;
  const int m16 = lane & 15;
  const int wr = w >> 2, wc = w & 3;

  // XCD-bijective swizzle (1024 % 8 == 0): each XCD gets 8 consecutive
  // rowTiles; A-panel (2 MB bf16) stays L2-resident per XCD.
  const int bswz = ((blockIdx.x & 7) << 7) | (blockIdx.x >> 3);
  const int rowBase = (bswz >> 4) << 8;
  const int colBase = (bswz & 15) << 8;
  const int wRow = rowBase + wr * 128;
  const int wCol = colBase + wc * 64;

  f32x4 acc[8][4];

  // ---- accumulator init = LoRA delta: t[256x16] @ lb[256x16]^T (K=16 pad) --
  {
    const int aIdx = rowBase >> 11;        // whole 256-row tile is one adapter
    short8 z = {0, 0, 0, 0, 0, 0, 0, 0};
    f32x4 cz = {0.f, 0.f, 0.f, 0.f};
    short8 atf[8], btf[4];
#pragma unroll
    for (int mi = 0; mi < 8; mi++) {
      if (quad < 2)   // k = quad*8+j < 16 valid, upper half zero-padded
        atf[mi] = *(const short8*)(tb + (size_t)(wRow + mi * 16 + m16) * 16 + quad * 8);
      else
        atf[mi] = z;
    }
#pragma unroll
    for (int ni = 0; ni < 4; ni++) {
      if (quad < 2)
        btf[ni] = *(const short8*)(lbb + ((size_t)aIdx * 4096 + (wCol + ni * 16 + m16)) * 16 + quad * 8);
      else
        btf[ni] = z;
    }
#pragma unroll
    for (int mi = 0; mi < 8; mi++)
#pragma unroll
      for (int ni = 0; ni < 4; ni++)
        acc[mi][ni] = __builtin_amdgcn_mfma_f32_16x16x32_bf16(atf[mi], btf[ni], cz, 0, 0, 0);
  }

  // ---- staging: thread tid owns LDS chunks {tid, tid+512, tid+1024, tid+1536}
  // of each 32 KB tile (linear dest = wave base + lane*16).  Global source is
  // pre-swizzled: row = tid>>3 (+64/128/192), col-chunk = (tid&7)^((tid>>3)&7).
  const int jsrc = ((tid & 7) ^ ((tid >> 3) & 7)) * 8;
  const unsigned short* gA = xb + (size_t)(rowBase + (tid >> 3)) * 4096 + jsrc;
  const unsigned short* gB = wb + (size_t)(colBase + (tid >> 3)) * 4096 + jsrc;

#define STAGE(T) do { const int p_ = (T) & 1;                                   \
    unsigned short* dA_ = &As[p_][0] + tid * 8;                                 \
    unsigned short* dB_ = &Bs[p_][0] + tid * 8;                                 \
    const unsigned short* sA_ = gA + (size_t)(T) * 64;                          \
    const unsigned short* sB_ = gB + (size_t)(T) * 64;                          \
    load16(sA_,                       dA_);                                     \
    load16(sA_ + (size_t) 64 * 4096,  dA_ +  512 * 8);                          \
    load16(sA_ + (size_t)128 * 4096,  dA_ + 1024 * 8);                          \
    load16(sA_ + (size_t)192 * 4096,  dA_ + 1536 * 8);                          \
    load16(sB_,                       dB_);                                     \
    load16(sB_ + (size_t) 64 * 4096,  dB_ +  512 * 8);                          \
    load16(sB_ + (size_t)128 * 4096,  dB_ + 1024 * 8);                          \
    load16(sB_ + (size_t)192 * 4096,  dB_ + 1536 * 8); } while (0)

  STAGE(0);
  asm volatile("s_waitcnt vmcnt(0)" ::: "memory");
  __builtin_amdgcn_s_barrier();

  // swizzled read column offsets (ushorts): chunk (quad+4*kk) ^ (row&7)
  const int c0 = ((quad)     ^ (m16 & 7)) * 8;   // kk = 0
  const int c1 = ((quad + 4) ^ (m16 & 7)) * 8;   // kk = 1
  const int aRow = (wr * 128 + m16) * 64;        // + mi*1024
  const int bRow = (wc * 64  + m16) * 64;        // + ni*1024

  for (int t = 0; t < 64; ++t) {
    const unsigned short* Ab = &As[t & 1][0] + aRow;
    const unsigned short* Bb = &Bs[t & 1][0] + bRow;
    short8 a[8], b0, b1, b2, b3;

    // ================= phase 1: quadrant (kk0, ni 0-1) =====================
#pragma unroll
    for (int mi = 0; mi < 8; mi++) a[mi] = *(const short8*)(Ab + mi * 1024 + c0);
    b0 = *(const short8*)(Bb + 0 * 1024 + c0);
    b1 = *(const short8*)(Bb + 1 * 1024 + c0);
    if (t + 1 < 64) STAGE(t + 1);              // all 8 prefetch loads, early
    __builtin_amdgcn_s_barrier();
    asm volatile("s_waitcnt lgkmcnt(0)" ::: "memory");
    __builtin_amdgcn_sched_barrier(0);
    __builtin_amdgcn_s_setprio(1);
#pragma unroll
    for (int mi = 0; mi < 8; mi++)
      acc[mi][0] = __builtin_amdgcn_mfma_f32_16x16x32_bf16(a[mi], b0, acc[mi][0], 0, 0, 0);
#pragma unroll
    for (int mi = 0; mi < 8; mi++)
      acc[mi][1] = __builtin_amdgcn_mfma_f32_16x16x32_bf16(a[mi], b1, acc[mi][1], 0, 0, 0);
    __builtin_amdgcn_s_setprio(0);
    __builtin_amdgcn_s_barrier();

    // ================= phase 2: quadrant (kk0, ni 2-3) =====================
    b2 = *(const short8*)(Bb + 2 * 1024 + c0);
    b3 = *(const short8*)(Bb + 3 * 1024 + c0);
    __builtin_amdgcn_s_barrier();
    asm volatile("s_waitcnt lgkmcnt(0)" ::: "memory");
    __builtin_amdgcn_sched_barrier(0);
    __builtin_amdgcn_s_setprio(1);
#pragma unroll
    for (int mi = 0; mi < 8; mi++)
      acc[mi][2] = __builtin_amdgcn_mfma_f32_16x16x32_bf16(a[mi], b2, acc[mi][2], 0, 0, 0);
#pragma unroll
    for (int mi = 0; mi < 8; mi++)
      acc[mi][3] = __builtin_amdgcn_mfma_f32_16x16x32_bf16(a[mi], b3, acc[mi][3], 0, 0, 0);
    __builtin_amdgcn_s_setprio(0);
    __builtin_amdgcn_s_barrier();

    // ================= phase 3: quadrant (kk1, ni 0-1) =====================
#pragma unroll
    for (int mi = 0; mi < 8; mi++) a[mi] = *(const short8*)(Ab + mi * 1024 + c1);
    b0 = *(const short8*)(Bb + 0 * 1024 + c1);
    b1 = *(const short8*)(Bb + 1 * 1024 + c1);
    __builtin_amdgcn_s_barrier();
    asm volatile("s_waitcnt lgkmcnt(0)" ::: "memory");
    __builtin_amdgcn_sched_barrier(0);
    __builtin_amdgcn_s_setprio(1);
#pragma unroll
    for (int mi = 0; mi < 8; mi++)
      acc[mi][0] = __builtin_amdgcn_mfma_f32_16x16x32_bf16(a[mi], b0, acc[mi][0], 0, 0, 0);
#pragma unroll
    for (int mi = 0; mi < 8; mi++)
      acc[mi][1] = __builtin_amdgcn_mfma_f32_16x16x32_bf16(a[mi], b1, acc[mi][1], 0, 0, 0);
    __builtin_amdgcn_s_setprio(0);
    __builtin_amdgcn_s_barrier();

    // ================= phase 4: quadrant (kk1, ni 2-3) =====================
    b2 = *(const short8*)(Bb + 2 * 1024 + c1);
    b3 = *(const short8*)(Bb + 3 * 1024 + c1);
    __builtin_amdgcn_s_barrier();
    asm volatile("s_waitcnt lgkmcnt(0)" ::: "memory");
    __builtin_amdgcn_sched_barrier(0);
    __builtin_amdgcn_s_setprio(1);
#pragma unroll
    for (int mi = 0; mi < 8; mi++)
      acc[mi][2] = __builtin_amdgcn_mfma_f32_16x16x32_bf16(a[mi], b2, acc[mi][2], 0, 0, 0);
#pragma unroll
    for (int mi = 0; mi < 8; mi++)
      acc[mi][3] = __builtin_amdgcn_mfma_f32_16x16x32_bf16(a[mi], b3, acc[mi][3], 0, 0, 0);
    __builtin_amdgcn_s_setprio(0);
    // tile t+1 loads (issued in phase 1, ~3 phases old) must land before the
    // closing barrier -> counted-in-spirit drain of OLD loads only.
    asm volatile("s_waitcnt vmcnt(0)" ::: "memory");
    __builtin_amdgcn_sched_barrier(0);
    __builtin_amdgcn_s_barrier();
  }
#undef STAGE

  // ---- epilogue: C/D layout col=lane&15, row=quad*4+reg; fp32 store --------
#pragma unroll
  for (int mi = 0; mi < 8; mi++) {
    const int row0 = wRow + mi * 16 + quad * 4;
#pragma unroll
    for (int ni = 0; ni < 4; ni++) {
      const int col = wCol + ni * 16 + m16;
      float* p = out + (size_t)row0 * 4096 + col;
#pragma unroll
      for (int r = 0; r < 4; r++)
        p[(size_t)r * 4096] = acc[mi][ni][r];
    }
  }
}

extern "C" void kernel_launch(void* const* d_in, const int* in_sizes, int n_in,
                              void* d_out, int out_size, void* d_ws, size_t ws_size,
                              hipStream_t stream) {
  const float* x  = (const float*)d_in[0];   // [8,2048,4096]
  const float* W  = (const float*)d_in[1];   // [4096,4096] (out,in)
  const float* la = (const float*)d_in[2];   // [8,16,4096]
  const float* lb = (const float*)d_in[3];   // [8,4096,16]
  float* out = (float*)d_out;                // [8,2048,4096] fp32

  const size_t NX  = 8ull * 2048 * 4096;     // 67108864
  const size_t NW  = 4096ull * 4096;         // 16777216
  const size_t NT  = 16384ull * 16;          // 262144
  const size_t NLB = 8ull * 4096 * 16;       // 524288
  unsigned short* xb  = (unsigned short*)d_ws;
  unsigned short* wbf = xb + NX;
  unsigned short* tb  = wbf + NW;
  unsigned short* lbb = tb + NT;
  if (ws_size < (NX + NW + NT + NLB) * sizeof(unsigned short)) return;

  convert_all_kernel<<<2048, 256, 0, stream>>>(x, xb, W, wbf, lb, lbb);
  lora_t_kernel<<<256, 256, 0, stream>>>(xb, la, tb);
  lora_gemm_kernel<<<1024, 512, 0, stream>>>(xb, wbf, tb, lbb, out);
}